// Round 11
// baseline (244.866 us; speedup 1.0000x reference)
//
#include <hip/hip_runtime.h>

#define NN    4096
#define OF    256
#define NH    8

typedef __attribute__((ext_vector_type(8))) short short8;
typedef __attribute__((ext_vector_type(4))) float f32x4;

__device__ __forceinline__ float bf2f(unsigned int u) {
    union { unsigned int i; float f; } v; v.i = u << 16; return v.f;
}
__device__ __forceinline__ unsigned short f2bf(float f) {
    union { float f; unsigned int i; } v; v.f = f;
    unsigned int x = v.i;
    return (unsigned short)((x + 0x7fffu + ((x >> 16) & 1u)) >> 16);
}
__device__ __forceinline__ unsigned int pk2bf(float a, float b) {
    return (unsigned int)f2bf(a) | ((unsigned int)f2bf(b) << 16);
}
__device__ __forceinline__ float asf(unsigned int u) {
    union { unsigned int i; float f; } v; v.i = u; return v.f;
}

// K0 (tiny, 256 blocks): dtype probe + zero lp/lc/Stot + W bf16x3 split.
__global__ __launch_bounds__(256) void k_pre(
    const float* __restrict__ adjf, const float* __restrict__ Wf,
    int* __restrict__ flag, unsigned short* __restrict__ Wbh,
    unsigned short* __restrict__ Wbl, float* __restrict__ zbase)
{
    __shared__ int viol;
    int t = threadIdx.x;
    int gid = blockIdx.x * 256 + t;              // 0..65535
    if (t == 0) viol = 0;
    __syncthreads();
    int bad = 0;
    for (int k = t; k < NN; k += 256) {          // 16KB: in-bounds either dtype
        float v = adjf[k];
        if (!(v == 0.0f || v == 1.0f)) bad = 1;
    }
    if (bad) atomicAdd(&viol, 1);
    __syncthreads();
    int f = viol > 0;
    if (t == 0) *flag = f;                       // same value from every block

    zbase[gid] = 0.f;                            // lp+lc (65536 floats)
    if (gid < 256) zbase[65536 + gid] = 0.f;     // Stot
    if (!f) {                                    // W split: 65536 elements
        float v = Wf[gid];
        unsigned short h = f2bf(v);
        Wbh[gid] = h; Wbl[gid] = f2bf(v - bf2f(h));
    }
}

// K1: proj (1024 blocks) — nf = x@W^T + b (MFMA).
// Changes for dense k_attn: (a) nf stored COLUMN-major (nfT[c][row]) so the
// attn B-fragment is a contiguous 16B load; (b) lc stored transposed
// (lcT[h][row]) for contiguous A-build loads; (c) apar/achd pre-scaled by
// log2(e) so attn uses native exp2 (v_exp_f32) with no per-element mul.
__global__ __launch_bounds__(256) void k_proj(
    const void* __restrict__ xraw, const void* __restrict__ Wraw,
    const void* __restrict__ braw, const void* __restrict__ araw,
    const int* __restrict__ flag,
    const unsigned short* __restrict__ Wbh, const unsigned short* __restrict__ Wbl,
    unsigned short* __restrict__ nfT, float* __restrict__ lp,
    float* __restrict__ lc, float* __restrict__ Stot)
{
    __shared__ unsigned short xh[16][264], xl[16][264];   // 16.5 KB

    int f = *flag;
    int t = threadIdx.x;
    int wave = t >> 6;
    int lane = t & 63;
    int pid = blockIdx.x;                        // [0,1024)

    int tid  = pid * 4 + wave;                   // 4096 wave-tiles
    int mt = tid >> 4, nt = tid & 15;            // mt identical across waves
    int lr = lane & 15;
    int kq = (lane >> 4) * 8;

    if (!f) {  // cooperative x-tile convert: rows [mt*16, mt*16+16)
        const float* xsrc = (const float*)xraw + (size_t)mt * 4096;
        #pragma unroll
        for (int q = 0; q < 16; q++) {
            int e = t + 256*q;                   // coalesced
            float v = xsrc[e];
            unsigned short h = f2bf(v);
            xh[e >> 8][e & 255] = h;
            xl[e >> 8][e & 255] = f2bf(v - bf2f(h));
        }
        __syncthreads();
    }

    size_t wo = (size_t)(nt*16 + lr)*OF + kq;
    f32x4 acc = {0.f, 0.f, 0.f, 0.f};
    if (f) {
        const short8* xp = reinterpret_cast<const short8*>(
            (const unsigned short*)xraw + (size_t)(mt*16 + lr)*OF + kq);
        const short8* wp = reinterpret_cast<const short8*>(
            (const unsigned short*)Wraw + wo);
        #pragma unroll
        for (int kk = 0; kk < OF/32; kk++)
            acc = __builtin_amdgcn_mfma_f32_16x16x32_bf16(xp[kk*4], wp[kk*4], acc, 0, 0, 0);
    } else {
        const short8* wh = reinterpret_cast<const short8*>(Wbh + wo);
        const short8* wl = reinterpret_cast<const short8*>(Wbl + wo);
        #pragma unroll
        for (int kk = 0; kk < OF/32; kk++) {
            short8 ah = *reinterpret_cast<const short8*>(&xh[lr][kk*32 + kq]);
            short8 al = *reinterpret_cast<const short8*>(&xl[lr][kk*32 + kq]);
            short8 bh = wh[kk*4], bl = wl[kk*4];
            acc = __builtin_amdgcn_mfma_f32_16x16x32_bf16(ah, bh, acc, 0, 0, 0);
            acc = __builtin_amdgcn_mfma_f32_16x16x32_bf16(ah, bl, acc, 0, 0, 0);
            acc = __builtin_amdgcn_mfma_f32_16x16x32_bf16(al, bh, acc, 0, 0, 0);
        }
    }

    int col  = nt*16 + lr;                       // C/D: col = lane&15
    int row0 = mt*16 + (lane >> 4) * 4;          //      row = quad*4 + reg
    int h = col >> 5, cc = col & 31;
    const float LOG2E = 1.4426950408889634f;
    float bias, apar, achd;
    if (f) {
        bias = bf2f((unsigned int)((const unsigned short*)braw)[col]);
        apar = bf2f((unsigned int)((const unsigned short*)araw)[h*64 + cc]);
        achd = bf2f((unsigned int)((const unsigned short*)araw)[h*64 + 32 + cc]);
    } else {
        bias = ((const float*)braw)[col];
        apar = ((const float*)araw)[h*64 + cc];
        achd = ((const float*)araw)[h*64 + 32 + cc];
    }
    apar *= LOG2E; achd *= LOG2E;                // logits pre-scaled to base-2

    float vv[4];
    #pragma unroll
    for (int r = 0; r < 4; r++) vv[r] = acc[r] + bias;

    // nfT[col][row] column-major store: 4 consecutive rows = one 8B store
    uint2 pkv;
    pkv.x = pk2bf(vv[0], vv[1]);
    pkv.y = pk2bf(vv[2], vv[3]);
    *reinterpret_cast<uint2*>(nfT + (size_t)col*NN + row0) = pkv;

    float st = 0.f, pr[4], cr[4];
    #pragma unroll
    for (int r = 0; r < 4; r++) {
        st += vv[r];
        pr[r] = vv[r] * apar;
        cr[r] = vv[r] * achd;
    }
    #pragma unroll
    for (int m = 1; m <= 8; m <<= 1) {
        #pragma unroll
        for (int r = 0; r < 4; r++) {
            pr[r] += __shfl_xor(pr[r], m, 64);
            cr[r] += __shfl_xor(cr[r], m, 64);
        }
    }
    if ((lane & 15) == 0) {
        #pragma unroll
        for (int r = 0; r < 4; r++) {
            atomicAdd(&lp[(row0 + r) * NH + h], pr[r]);       // lp[i][h]
            atomicAdd(&lc[(size_t)h * NN + row0 + r], cr[r]); // lcT[h][j]
        }
    }
    st += __shfl_down(st, 16, 64);
    st += __shfl_down(st, 32, 64);
    if (lane < 16) atomicAdd(&Stot[col], st);
}

// K2: DENSE MFMA attention. 256 blocks x 512 thr; block = 16 output rows,
// wave w = head w. Per j-tile of 32: build bf16 P-fragment in registers
// (P = adj_mask * (2^lrelu(lp'+lc') - 1), logits pre-scaled to base-2),
// 2x mfma_16x16x32_bf16 vs column-major nfT. Z sums the bf16-ROUNDED
// weights (self-consistent softmax). Streaming adj re-read (67MB) replaces
// the latency-bound sparse gather; no barriers in the main loop.
__global__ __launch_bounds__(512) void k_attn(
    const int* __restrict__ flag, const float* __restrict__ adjf,
    const float* __restrict__ lp, const float* __restrict__ lc,
    const unsigned short* __restrict__ nfT, const float* __restrict__ Stot,
    void* __restrict__ outv)
{
    __shared__ float zsh[8][16];

    int i0 = blockIdx.x * 16;
    int t = threadIdx.x;
    int w = t >> 6;                      // head
    int lane = t & 63;
    int r = lane & 15;                   // A-row / D-col index
    int q = lane >> 4;                   // k-quad
    int f = *flag;

    float lpr = lp[(i0 + r) * NH + w];   // base-2-scaled logit_parent for row r
    const float* lcr = lc + (size_t)w * NN;                        // lcT[h][.]
    const unsigned short* b0p = nfT + (size_t)(w*32      + r) * NN;
    const unsigned short* b1p = nfT + (size_t)(w*32 + 16 + r) * NN;

    f32x4 acc0 = {0.f,0.f,0.f,0.f}, acc1 = {0.f,0.f,0.f,0.f};
    float zacc = 0.f;

    for (int j0 = 0; j0 < NN; j0 += 32) {
        int jq = j0 + q*8;
        // B fragments: contiguous 16B from column-major nfT
        short8 B0 = *reinterpret_cast<const short8*>(b0p + jq);
        short8 B1 = *reinterpret_cast<const short8*>(b1p + jq);
        // logit_child slice: contiguous 32B
        float4 lca = *reinterpret_cast<const float4*>(lcr + jq);
        float4 lcb = *reinterpret_cast<const float4*>(lcr + jq + 4);
        float lv[8] = {lca.x, lca.y, lca.z, lca.w, lcb.x, lcb.y, lcb.z, lcb.w};
        // adjacency mask (values are exactly 0.0/1.0)
        float mk[8];
        if (f) {
            uint4 av = *reinterpret_cast<const uint4*>(
                (const unsigned short*)adjf + (size_t)(i0 + r) * NN + jq);
            unsigned int wd[4] = {av.x, av.y, av.z, av.w};
            #pragma unroll
            for (int u = 0; u < 4; u++) {
                mk[2*u]   = bf2f(wd[u] & 0xffffu);
                mk[2*u+1] = bf2f(wd[u] >> 16);
            }
        } else {
            float4 a0 = *reinterpret_cast<const float4*>(
                adjf + (size_t)(i0 + r) * NN + jq);
            float4 a1 = *reinterpret_cast<const float4*>(
                adjf + (size_t)(i0 + r) * NN + jq + 4);
            mk[0]=a0.x; mk[1]=a0.y; mk[2]=a0.z; mk[3]=a0.w;
            mk[4]=a1.x; mk[5]=a1.y; mk[6]=a1.z; mk[7]=a1.w;
        }
        // P elements: mask * (2^lrelu(s') - 1); clamp before exp (inf*0=NaN)
        float wv[8];
        #pragma unroll
        for (int e = 0; e < 8; e++) {
            float s = lpr + lv[e];
            s = fmaxf(s, 0.2f * s);              // leaky relu (scale commutes)
            s = fminf(s, 101.0f);                // = 70 * log2(e)
            wv[e] = (exp2f(s) - 1.0f) * mk[e];
        }
        // pack to bf16 A-frag; Z sums the ROUNDED values (self-consistent)
        union { unsigned int u[4]; short8 s8; } A;
        #pragma unroll
        for (int p = 0; p < 4; p++) {
            unsigned int pk;
            asm("v_cvt_pk_bf16_f32 %0, %1, %2" : "=v"(pk)
                : "v"(wv[2*p]), "v"(wv[2*p+1]));
            A.u[p] = pk;
            zacc += asf(pk << 16) + asf(pk & 0xffff0000u);
        }
        acc0 = __builtin_amdgcn_mfma_f32_16x16x32_bf16(A.s8, B0, acc0, 0, 0, 0);
        acc1 = __builtin_amdgcn_mfma_f32_16x16x32_bf16(A.s8, B1, acc1, 0, 0, 0);
    }

    // Z[r] = sum over the 4 k-quads (lanes r, r+16, r+32, r+48)
    zacc += __shfl_xor(zacc, 16, 64);
    zacc += __shfl_xor(zacc, 32, 64);
    if (lane < 16) zsh[w][lane] = zacc;
    __syncthreads();                             // cheap: once per kernel

    // epilogue: C/D row = 4q+reg, col = r
    f32x4 z4 = *reinterpret_cast<f32x4*>(&zsh[w][q*4]);
    int c0 = w*32 + r, c1 = c0 + 16;
    float st0 = Stot[c0], st1 = Stot[c1];
    #pragma unroll
    for (int reg = 0; reg < 4; reg++) {
        float iz = 1.0f / (4096.0f + z4[reg]);
        float o0 = (st0 + acc0[reg]) * iz;
        float o1 = (st1 + acc1[reg]) * iz;
        int row = i0 + 4*q + reg;
        if (f) {
            ((unsigned short*)outv)[(size_t)row*OF + c0] = f2bf(o0);
            ((unsigned short*)outv)[(size_t)row*OF + c1] = f2bf(o1);
        } else {
            ((float*)outv)[(size_t)row*OF + c0] = o0;
            ((float*)outv)[(size_t)row*OF + c1] = o1;
        }
    }
}

extern "C" void kernel_launch(void* const* d_in, const int* in_sizes, int n_in,
                              void* d_out, int out_size, void* d_ws, size_t ws_size,
                              hipStream_t stream) {
    const void* x   = d_in[0];  // [4096,256]
    const void* W   = d_in[1];  // [256,256]
    const void* b   = d_in[2];  // [256]
    const void* a   = d_in[3];  // [8,64]
    const void* adj = d_in[4];  // [4096,4096]

    char* ws = (char*)d_ws;
    const size_t MB = 1024u*1024u, KB = 1024u;
    unsigned short* nfT  = (unsigned short*)(ws);                 // 2 MB (col-major)
    float*          lp   = (float*)(ws + 2*MB);                   // 128 KB
    float*          lc   = (float*)(ws + 2*MB + 128*KB);          // 128 KB (lcT[h][j])
    float*          Stot = (float*)(ws + 2*MB + 256*KB);          // 1 KB
    int*            flag = (int*)(ws + 2*MB + 257*KB);            // 4 B (1KB pad)
    unsigned short* Wbh  = (unsigned short*)(ws + 6*MB);          // 128 KB
    unsigned short* Wbl  = (unsigned short*)(ws + 6*MB + 128*KB); // 128 KB

    k_pre  <<<256,  256, 0, stream>>>((const float*)adj, (const float*)W,
                                      flag, Wbh, Wbl, lp);
    k_proj <<<1024, 256, 0, stream>>>(x, W, b, a, flag, Wbh, Wbl,
                                      nfT, lp, lc, Stot);
    k_attn <<<256,  512, 0, stream>>>(flag, (const float*)adj, lp, lc,
                                      nfT, Stot, d_out);
}